// Round 9
// baseline (878.152 us; speedup 1.0000x reference)
//
#include <hip/hip_runtime.h>

#define BATCH 4
#define NPTS  16384
#define SPTS  4096
#define C1    128
#define C2    256
#define CIN   384
#define H1    256
#define H2    128
#define MROWS (BATCH * NPTS)   // 65536

// ---------------------------------------------------------------------------
// K1: 3-NN + inverse-distance weights, f32, targeting gold = XLA-CPU jit of
// the jax reference with LLVM fp-contraction (DAGCombiner fuses operand-0
// fmul first):
//   sq   = fma(z,z, fma(x,x, y*y))     (fused mul+reduce, contracted)
//   dot  = fma(z,pz, fma(y,py, x*px))  (dot_general k=3, sequential fma)
//   t1   = sq1 + sq2                   (plain add: fma nodes don't re-fuse)
//   d2   = fma(-2, dot, t1)            (fsub(t1, fmul(2,dot)) contracted)
// Evidence trail: R3(all plain)=0.9453; R8(dot→fma only)=0.8623 — the
// dominant defect query was fixed by dot=fma, so we're converging on gold's
// bit pattern sub-expression by sub-expression.
// Strict-< insertion = lax.top_k stable tie-break (lower index wins).
// ---------------------------------------------------------------------------
__global__ __launch_bounds__(256) void knn_kernel(
    const float* __restrict__ xyz1, const float* __restrict__ xyz2,
    int* __restrict__ idx3, float* __restrict__ w3) {
#pragma clang fp contract(off)
  __shared__ float4 pts[SPTS];  // {px,py,pz,sq2} 64 KB
  const int b = blockIdx.y;
  const float* src = xyz2 + (size_t)b * SPTS * 3;
  for (int i = threadIdx.x; i < SPTS; i += 256) {
    float px = src[i * 3 + 0], py = src[i * 3 + 1], pz = src[i * 3 + 2];
    float s = fmaf(pz, pz, fmaf(px, px, py * py));  // XLA-contracted sq
    pts[i] = make_float4(px, py, pz, s);
  }
  __syncthreads();

  const int n = blockIdx.x * 256 + threadIdx.x;
  const size_t row = (size_t)b * NPTS + n;
  const float qx = xyz1[row * 3 + 0], qy = xyz1[row * 3 + 1], qz = xyz1[row * 3 + 2];
  const float sq1 = fmaf(qz, qz, fmaf(qx, qx, qy * qy));  // XLA-contracted sq

  float b0 = 1e30f, b1v = 1e30f, b2v = 1e30f;
  int i0 = 0, i1 = 0, i2 = 0;
  for (int s = 0; s < SPTS; ++s) {
    float4 p = pts[s];
    float dot = fmaf(qz, p.z, fmaf(qy, p.y, qx * p.x));  // fma chain
    float t1 = sq1 + p.w;                                // plain add
    float d = fmaf(-2.0f, dot, t1);                      // contracted sub
    if (d < b2v) {
      if (d < b1v) {
        b2v = b1v; i2 = i1;
        if (d < b0) { b1v = b0; i1 = i0; b0 = d; i0 = s; }
        else        { b1v = d;  i1 = s; }
      } else { b2v = d; i2 = s; }
    }
  }
  float r0 = 1.0f / (b0 + 1e-8f);
  float r1 = 1.0f / (b1v + 1e-8f);
  float r2 = 1.0f / (b2v + 1e-8f);
  float rs = (r0 + r1) + r2;
  idx3[row * 3 + 0] = i0; idx3[row * 3 + 1] = i1; idx3[row * 3 + 2] = i2;
  w3[row * 3 + 0] = r0 / rs;
  w3[row * 3 + 1] = r1 / rs;
  w3[row * 3 + 2] = r2 / rs;
}

#define BM 64
#define BN 64
#define BK 32
#define LPAD 4

// ---------------------------------------------------------------------------
// K2: GEMM1 with interpolation fused into the A-tile load (R5-identical).
// ---------------------------------------------------------------------------
__global__ __launch_bounds__(256) void gemm1_kernel(
    const float* __restrict__ features2, const float* __restrict__ features1,
    const int* __restrict__ idx3, const float* __restrict__ w3,
    const float* __restrict__ W1, const float* __restrict__ b1,
    float* __restrict__ h1) {
  __shared__ float As[BK][BM + LPAD];
  __shared__ float Bs[BK][BN + LPAD];
  const int t = threadIdx.x;
  const int m0 = blockIdx.x * BM;
  const int n0 = blockIdx.y * BN;
  const int tx = t & 15, ty = t >> 4;

  const int ar = t >> 2;
  const int cq = (t & 3) * 8;
  const size_t arow = m0 + ar;
  const int ab = (int)(arow >> 14);
  const float* f2 = features2 + (size_t)ab * SPTS * C2;
  const size_t r0i = (size_t)idx3[arow * 3 + 0] * C2;
  const size_t r1i = (size_t)idx3[arow * 3 + 1] * C2;
  const size_t r2i = (size_t)idx3[arow * 3 + 2] * C2;
  const float w0 = w3[arow * 3 + 0];
  const float w1 = w3[arow * 3 + 1];
  const float w2 = w3[arow * 3 + 2];
  const float* f1row = features1 + arow * C1;

  float acc[4][4] = {};

  for (int k0 = 0; k0 < CIN; k0 += BK) {
    if (k0 < C2) {
#pragma unroll
      for (int j = 0; j < 8; ++j) {
        int col = k0 + cq + j;
        float v = w0 * f2[r0i + col] + w1 * f2[r1i + col] + w2 * f2[r2i + col];
        As[cq + j][ar] = v;
      }
    } else {
#pragma unroll
      for (int j = 0; j < 8; ++j) {
        int col = k0 + cq + j;
        As[cq + j][ar] = f1row[col - C2];
      }
    }
#pragma unroll
    for (int p = 0; p < 8; ++p) {
      int lin = t + p * 256;
      int c = lin & 31, h = lin >> 5;
      Bs[c][h] = W1[(size_t)(n0 + h) * CIN + k0 + c];
    }
    __syncthreads();
#pragma unroll
    for (int c = 0; c < BK; ++c) {
      float4 av = *(const float4*)&As[c][ty * 4];
      float4 bv = *(const float4*)&Bs[c][tx * 4];
      float aa[4] = {av.x, av.y, av.z, av.w};
      float bb[4] = {bv.x, bv.y, bv.z, bv.w};
#pragma unroll
      for (int i = 0; i < 4; ++i)
#pragma unroll
        for (int j = 0; j < 4; ++j) acc[i][j] = fmaf(aa[i], bb[j], acc[i][j]);
    }
    __syncthreads();
  }
  float4 bias = *(const float4*)&b1[n0 + tx * 4];
#pragma unroll
  for (int i = 0; i < 4; ++i) {
    size_t row = m0 + ty * 4 + i;
    float4 o = make_float4(acc[i][0] + bias.x, acc[i][1] + bias.y,
                           acc[i][2] + bias.z, acc[i][3] + bias.w);
    *(float4*)&h1[row * H1 + n0 + tx * 4] = o;
  }
}

// ---------------------------------------------------------------------------
// K3: GEMM2 with BN1+ReLU fused into A-tile load; writes into d_out.
// ---------------------------------------------------------------------------
__global__ __launch_bounds__(256) void gemm2_kernel(
    const float* __restrict__ h1, const float* __restrict__ scale1,
    const float* __restrict__ shift1, const float* __restrict__ W2,
    const float* __restrict__ b2, float* __restrict__ h2) {
  __shared__ float As[BK][BM + LPAD];
  __shared__ float Bs[BK][BN + LPAD];
  const int t = threadIdx.x;
  const int m0 = blockIdx.x * BM;
  const int n0 = blockIdx.y * BN;
  const int tx = t & 15, ty = t >> 4;
  float acc[4][4] = {};

  for (int k0 = 0; k0 < H1; k0 += BK) {
#pragma unroll
    for (int p = 0; p < 8; ++p) {
      int lin = t + p * 256;
      int c = lin & 31, r = lin >> 5;
      size_t row = m0 + r;
      int col = k0 + c;
      float v = h1[row * H1 + col];
      v = fmaf(v, scale1[col], shift1[col]);
      As[c][r] = fmaxf(v, 0.0f);
    }
#pragma unroll
    for (int p = 0; p < 8; ++p) {
      int lin = t + p * 256;
      int c = lin & 31, h = lin >> 5;
      Bs[c][h] = W2[(size_t)(n0 + h) * H1 + k0 + c];
    }
    __syncthreads();
#pragma unroll
    for (int c = 0; c < BK; ++c) {
      float4 av = *(const float4*)&As[c][ty * 4];
      float4 bv = *(const float4*)&Bs[c][tx * 4];
      float aa[4] = {av.x, av.y, av.z, av.w};
      float bb[4] = {bv.x, bv.y, bv.z, bv.w};
#pragma unroll
      for (int i = 0; i < 4; ++i)
#pragma unroll
        for (int j = 0; j < 4; ++j) acc[i][j] = fmaf(aa[i], bb[j], acc[i][j]);
    }
    __syncthreads();
  }
  float4 bias = *(const float4*)&b2[n0 + tx * 4];
#pragma unroll
  for (int i = 0; i < 4; ++i) {
    size_t row = m0 + ty * 4 + i;
    float4 o = make_float4(acc[i][0] + bias.x, acc[i][1] + bias.y,
                           acc[i][2] + bias.z, acc[i][3] + bias.w);
    *(float4*)&h2[row * H2 + n0 + tx * 4] = o;
  }
}

// ---------------------------------------------------------------------------
// Column sum/sumsq (fp64 accumulators) for BN stats.
// ---------------------------------------------------------------------------
__global__ void colstats_kernel(const float* __restrict__ h,
                                double* __restrict__ sum,
                                double* __restrict__ sumsq, int C,
                                int rowsPerBlock) {
  const int c = threadIdx.x;
  const size_t row0 = (size_t)blockIdx.x * rowsPerBlock;
  double s = 0.0, s2 = 0.0;
  const float* p = h + row0 * C + c;
  for (int r = 0; r < rowsPerBlock; ++r) {
    double v = (double)p[(size_t)r * C];
    s += v;
    s2 += v * v;
  }
  atomicAdd(&sum[c], s);
  atomicAdd(&sumsq[c], s2);
}

__global__ void finalize_kernel(const double* __restrict__ sum,
                                const double* __restrict__ sumsq,
                                const float* __restrict__ g,
                                const float* __restrict__ be,
                                float* __restrict__ scale,
                                float* __restrict__ shift) {
  const int c = threadIdx.x;
  const double invM = 1.0 / (double)MROWS;
  double mean = sum[c] * invM;
  double var = sumsq[c] * invM - mean * mean;
  double sc = (double)g[c] / sqrt(var + 1e-5);
  scale[c] = (float)sc;
  shift[c] = (float)((double)be[c] - mean * sc);
}

// In-place: io = relu(io*scale2 + shift2), float4-vectorized.
__global__ __launch_bounds__(256) void final_kernel(
    float* __restrict__ io, const float* __restrict__ scale2,
    const float* __restrict__ shift2) {
  const size_t i = (size_t)blockIdx.x * 256 + threadIdx.x;
  const int col4 = (int)(i & 31);
  float4 h = ((float4*)io)[i];
  float4 sc = ((const float4*)scale2)[col4];
  float4 sh = ((const float4*)shift2)[col4];
  float4 o;
  o.x = fmaxf(fmaf(h.x, sc.x, sh.x), 0.0f);
  o.y = fmaxf(fmaf(h.y, sc.y, sh.y), 0.0f);
  o.z = fmaxf(fmaf(h.z, sc.z, sh.z), 0.0f);
  o.w = fmaxf(fmaf(h.w, sc.w, sh.w), 0.0f);
  ((float4*)io)[i] = o;
}

extern "C" void kernel_launch(void* const* d_in, const int* in_sizes, int n_in,
                              void* d_out, int out_size, void* d_ws,
                              size_t ws_size, hipStream_t stream) {
  const float* xyz1      = (const float*)d_in[0];
  const float* xyz2      = (const float*)d_in[1];
  const float* features1 = (const float*)d_in[2];
  const float* features2 = (const float*)d_in[3];
  const float* W1  = (const float*)d_in[4];
  const float* b1  = (const float*)d_in[5];
  const float* g1  = (const float*)d_in[6];
  const float* be1 = (const float*)d_in[7];
  const float* W2  = (const float*)d_in[8];
  const float* b2  = (const float*)d_in[9];
  const float* g2  = (const float*)d_in[10];
  const float* be2 = (const float*)d_in[11];
  float* out = (float*)d_out;

  // Workspace (~66 MB): h1 | w3 | idx3 | fp64 sums | scale/shift.
  char* wsb   = (char*)d_ws;
  float* h1   = (float*)wsb;                               // 64 MB
  float* w3   = (float*)(wsb + (size_t)MROWS * H1 * 4);
  int* idx3   = (int*)(wsb + (size_t)MROWS * H1 * 4 + (size_t)MROWS * 3 * 4);
  double* sums = (double*)((char*)idx3 + (size_t)MROWS * 3 * 4);
  double* sum1 = sums;
  double* sq1s = sums + 256;
  double* sum2 = sums + 512;
  double* sq2s = sums + 640;
  float* ss    = (float*)(sums + 768);
  float* scale1 = ss;
  float* shift1 = ss + 256;
  float* scale2 = ss + 512;
  float* shift2 = ss + 640;

  hipMemsetAsync(sums, 0, 768 * sizeof(double), stream);

  knn_kernel<<<dim3(NPTS / 256, BATCH), 256, 0, stream>>>(xyz1, xyz2, idx3, w3);
  gemm1_kernel<<<dim3(MROWS / BM, H1 / BN), 256, 0, stream>>>(
      features2, features1, idx3, w3, W1, b1, h1);
  colstats_kernel<<<256, H1, 0, stream>>>(h1, sum1, sq1s, H1, MROWS / 256);
  finalize_kernel<<<1, H1, 0, stream>>>(sum1, sq1s, g1, be1, scale1, shift1);
  gemm2_kernel<<<dim3(MROWS / BM, H2 / BN), 256, 0, stream>>>(h1, scale1, shift1,
                                                              W2, b2, out);
  colstats_kernel<<<256, H2, 0, stream>>>(out, sum2, sq2s, H2, MROWS / 256);
  finalize_kernel<<<1, H2, 0, stream>>>(sum2, sq2s, g2, be2, scale2, shift2);
  final_kernel<<<(MROWS * H2 / 4) / 256, 256, 0, stream>>>(out, scale2, shift2);
}

// Round 10
// 612.470 us; speedup vs baseline: 1.4338x; 1.4338x over previous
//
#include <hip/hip_runtime.h>

#define BATCH 4
#define NPTS  16384
#define SPTS  4096
#define C1    128
#define C2    256
#define CIN   384
#define H1    256
#define H2    128
#define MROWS (BATCH * NPTS)   // 65536

#define CHUNK  512
#define NCHUNK (SPTS / CHUNK)  // 8

// ---------------------------------------------------------------------------
// KNN phase 1: per-chunk top-3. FROZEN ARITHMETIC (matches gold's XLA-CPU
// contraction — verified passing R9, absmax 0.03125):
//   sq  = fma(z,z, fma(x,x, y*y))
//   dot = fma(qz,pz, fma(qy,py, qx*px))
//   t1  = sq1 + sq2        (plain)
//   d2  = fma(-2, dot, t1)
// Strict-< insertion, global candidate index; per-chunk results are the
// stable (d, idx)-ordered top-3 of that chunk.
// R9 bottleneck: grid was 256 blocks = 1 block/CU = 1 wave/SIMD, VALUBusy
// 22%, occupancy 11.7% -> latency-bound. Splitting candidates 8x raises
// blocks to 2048 (8/CU) for latency hiding; LDS cut 64KB -> 8KB.
// ---------------------------------------------------------------------------
__global__ __launch_bounds__(256) void knn_part_kernel(
    const float* __restrict__ xyz1, const float* __restrict__ xyz2,
    float* __restrict__ pd, int* __restrict__ pi) {
#pragma clang fp contract(off)
  __shared__ float4 pts[CHUNK];  // 8 KB
  const int b = blockIdx.z;
  const int chunk = blockIdx.y;
  const int c0 = chunk * CHUNK;
  const float* src = xyz2 + ((size_t)b * SPTS + c0) * 3;
  for (int i = threadIdx.x; i < CHUNK; i += 256) {
    float px = src[i * 3 + 0], py = src[i * 3 + 1], pz = src[i * 3 + 2];
    float s = fmaf(pz, pz, fmaf(px, px, py * py));
    pts[i] = make_float4(px, py, pz, s);
  }
  __syncthreads();

  const int n = blockIdx.x * 256 + threadIdx.x;
  const size_t row = (size_t)b * NPTS + n;
  const float qx = xyz1[row * 3 + 0], qy = xyz1[row * 3 + 1], qz = xyz1[row * 3 + 2];
  const float sq1 = fmaf(qz, qz, fmaf(qx, qx, qy * qy));

  float b0 = 1e30f, b1v = 1e30f, b2v = 1e30f;
  int i0 = 0, i1 = 0, i2 = 0;
  for (int s = 0; s < CHUNK; ++s) {
    float4 p = pts[s];
    float dot = fmaf(qz, p.z, fmaf(qy, p.y, qx * p.x));
    float t1 = sq1 + p.w;
    float d = fmaf(-2.0f, dot, t1);
    if (d < b2v) {
      int gi = c0 + s;
      if (d < b1v) {
        b2v = b1v; i2 = i1;
        if (d < b0) { b1v = b0; i1 = i0; b0 = d; i0 = gi; }
        else        { b1v = d;  i1 = gi; }
      } else { b2v = d; i2 = gi; }
    }
  }
  const size_t o = (row * NCHUNK + chunk) * 3;
  pd[o + 0] = b0;  pd[o + 1] = b1v; pd[o + 2] = b2v;
  pi[o + 0] = i0;  pi[o + 1] = i1;  pi[o + 2] = i2;
}

// ---------------------------------------------------------------------------
// KNN phase 2: merge 8 partial top-3s (chunks ascending, entries ascending =
// stable (d, idx) order) then compute weights with R9's exact op order.
// ---------------------------------------------------------------------------
__global__ __launch_bounds__(256) void knn_merge_kernel(
    const float* __restrict__ pd, const int* __restrict__ pi,
    int* __restrict__ idx3, float* __restrict__ w3) {
#pragma clang fp contract(off)
  const size_t row = (size_t)blockIdx.x * 256 + threadIdx.x;
  const size_t base = row * (NCHUNK * 3);
  float b0 = 1e30f, b1v = 1e30f, b2v = 1e30f;
  int i0 = 0, i1 = 0, i2 = 0;
#pragma unroll
  for (int k = 0; k < NCHUNK * 3; ++k) {
    float d = pd[base + k];
    int gi = pi[base + k];
    if (d < b2v) {
      if (d < b1v) {
        b2v = b1v; i2 = i1;
        if (d < b0) { b1v = b0; i1 = i0; b0 = d; i0 = gi; }
        else        { b1v = d;  i1 = gi; }
      } else { b2v = d; i2 = gi; }
    }
  }
  float r0 = 1.0f / (b0 + 1e-8f);
  float r1 = 1.0f / (b1v + 1e-8f);
  float r2 = 1.0f / (b2v + 1e-8f);
  float rs = (r0 + r1) + r2;
  idx3[row * 3 + 0] = i0; idx3[row * 3 + 1] = i1; idx3[row * 3 + 2] = i2;
  w3[row * 3 + 0] = r0 / rs;
  w3[row * 3 + 1] = r1 / rs;
  w3[row * 3 + 2] = r2 / rs;
}

#define BM 64
#define BN 64
#define BK 32
#define LPAD 4

// ---------------------------------------------------------------------------
// GEMM1 with interpolation fused into the A-tile load (R9-identical).
// ---------------------------------------------------------------------------
__global__ __launch_bounds__(256) void gemm1_kernel(
    const float* __restrict__ features2, const float* __restrict__ features1,
    const int* __restrict__ idx3, const float* __restrict__ w3,
    const float* __restrict__ W1, const float* __restrict__ b1,
    float* __restrict__ h1) {
  __shared__ float As[BK][BM + LPAD];
  __shared__ float Bs[BK][BN + LPAD];
  const int t = threadIdx.x;
  const int m0 = blockIdx.x * BM;
  const int n0 = blockIdx.y * BN;
  const int tx = t & 15, ty = t >> 4;

  const int ar = t >> 2;
  const int cq = (t & 3) * 8;
  const size_t arow = m0 + ar;
  const int ab = (int)(arow >> 14);
  const float* f2 = features2 + (size_t)ab * SPTS * C2;
  const size_t r0i = (size_t)idx3[arow * 3 + 0] * C2;
  const size_t r1i = (size_t)idx3[arow * 3 + 1] * C2;
  const size_t r2i = (size_t)idx3[arow * 3 + 2] * C2;
  const float w0 = w3[arow * 3 + 0];
  const float w1 = w3[arow * 3 + 1];
  const float w2 = w3[arow * 3 + 2];
  const float* f1row = features1 + arow * C1;

  float acc[4][4] = {};

  for (int k0 = 0; k0 < CIN; k0 += BK) {
    if (k0 < C2) {
#pragma unroll
      for (int j = 0; j < 8; ++j) {
        int col = k0 + cq + j;
        float v = w0 * f2[r0i + col] + w1 * f2[r1i + col] + w2 * f2[r2i + col];
        As[cq + j][ar] = v;
      }
    } else {
#pragma unroll
      for (int j = 0; j < 8; ++j) {
        int col = k0 + cq + j;
        As[cq + j][ar] = f1row[col - C2];
      }
    }
#pragma unroll
    for (int p = 0; p < 8; ++p) {
      int lin = t + p * 256;
      int c = lin & 31, h = lin >> 5;
      Bs[c][h] = W1[(size_t)(n0 + h) * CIN + k0 + c];
    }
    __syncthreads();
#pragma unroll
    for (int c = 0; c < BK; ++c) {
      float4 av = *(const float4*)&As[c][ty * 4];
      float4 bv = *(const float4*)&Bs[c][tx * 4];
      float aa[4] = {av.x, av.y, av.z, av.w};
      float bb[4] = {bv.x, bv.y, bv.z, bv.w};
#pragma unroll
      for (int i = 0; i < 4; ++i)
#pragma unroll
        for (int j = 0; j < 4; ++j) acc[i][j] = fmaf(aa[i], bb[j], acc[i][j]);
    }
    __syncthreads();
  }
  float4 bias = *(const float4*)&b1[n0 + tx * 4];
#pragma unroll
  for (int i = 0; i < 4; ++i) {
    size_t row = m0 + ty * 4 + i;
    float4 o = make_float4(acc[i][0] + bias.x, acc[i][1] + bias.y,
                           acc[i][2] + bias.z, acc[i][3] + bias.w);
    *(float4*)&h1[row * H1 + n0 + tx * 4] = o;
  }
}

// ---------------------------------------------------------------------------
// GEMM2 with BN1+ReLU fused into A-tile load; writes into d_out.
// ---------------------------------------------------------------------------
__global__ __launch_bounds__(256) void gemm2_kernel(
    const float* __restrict__ h1, const float* __restrict__ scale1,
    const float* __restrict__ shift1, const float* __restrict__ W2,
    const float* __restrict__ b2, float* __restrict__ h2) {
  __shared__ float As[BK][BM + LPAD];
  __shared__ float Bs[BK][BN + LPAD];
  const int t = threadIdx.x;
  const int m0 = blockIdx.x * BM;
  const int n0 = blockIdx.y * BN;
  const int tx = t & 15, ty = t >> 4;
  float acc[4][4] = {};

  for (int k0 = 0; k0 < H1; k0 += BK) {
#pragma unroll
    for (int p = 0; p < 8; ++p) {
      int lin = t + p * 256;
      int c = lin & 31, r = lin >> 5;
      size_t row = m0 + r;
      int col = k0 + c;
      float v = h1[row * H1 + col];
      v = fmaf(v, scale1[col], shift1[col]);
      As[c][r] = fmaxf(v, 0.0f);
    }
#pragma unroll
    for (int p = 0; p < 8; ++p) {
      int lin = t + p * 256;
      int c = lin & 31, h = lin >> 5;
      Bs[c][h] = W2[(size_t)(n0 + h) * H1 + k0 + c];
    }
    __syncthreads();
#pragma unroll
    for (int c = 0; c < BK; ++c) {
      float4 av = *(const float4*)&As[c][ty * 4];
      float4 bv = *(const float4*)&Bs[c][tx * 4];
      float aa[4] = {av.x, av.y, av.z, av.w};
      float bb[4] = {bv.x, bv.y, bv.z, bv.w};
#pragma unroll
      for (int i = 0; i < 4; ++i)
#pragma unroll
        for (int j = 0; j < 4; ++j) acc[i][j] = fmaf(aa[i], bb[j], acc[i][j]);
    }
    __syncthreads();
  }
  float4 bias = *(const float4*)&b2[n0 + tx * 4];
#pragma unroll
  for (int i = 0; i < 4; ++i) {
    size_t row = m0 + ty * 4 + i;
    float4 o = make_float4(acc[i][0] + bias.x, acc[i][1] + bias.y,
                           acc[i][2] + bias.z, acc[i][3] + bias.w);
    *(float4*)&h2[row * H2 + n0 + tx * 4] = o;
  }
}

// ---------------------------------------------------------------------------
// Column sum/sumsq (fp64 accumulators) for BN stats.
// ---------------------------------------------------------------------------
__global__ void colstats_kernel(const float* __restrict__ h,
                                double* __restrict__ sum,
                                double* __restrict__ sumsq, int C,
                                int rowsPerBlock) {
  const int c = threadIdx.x;
  const size_t row0 = (size_t)blockIdx.x * rowsPerBlock;
  double s = 0.0, s2 = 0.0;
  const float* p = h + row0 * C + c;
  for (int r = 0; r < rowsPerBlock; ++r) {
    double v = (double)p[(size_t)r * C];
    s += v;
    s2 += v * v;
  }
  atomicAdd(&sum[c], s);
  atomicAdd(&sumsq[c], s2);
}

__global__ void finalize_kernel(const double* __restrict__ sum,
                                const double* __restrict__ sumsq,
                                const float* __restrict__ g,
                                const float* __restrict__ be,
                                float* __restrict__ scale,
                                float* __restrict__ shift) {
  const int c = threadIdx.x;
  const double invM = 1.0 / (double)MROWS;
  double mean = sum[c] * invM;
  double var = sumsq[c] * invM - mean * mean;
  double sc = (double)g[c] / sqrt(var + 1e-5);
  scale[c] = (float)sc;
  shift[c] = (float)((double)be[c] - mean * sc);
}

// In-place: io = relu(io*scale2 + shift2), float4-vectorized.
__global__ __launch_bounds__(256) void final_kernel(
    float* __restrict__ io, const float* __restrict__ scale2,
    const float* __restrict__ shift2) {
  const size_t i = (size_t)blockIdx.x * 256 + threadIdx.x;
  const int col4 = (int)(i & 31);
  float4 h = ((float4*)io)[i];
  float4 sc = ((const float4*)scale2)[col4];
  float4 sh = ((const float4*)shift2)[col4];
  float4 o;
  o.x = fmaxf(fmaf(h.x, sc.x, sh.x), 0.0f);
  o.y = fmaxf(fmaf(h.y, sc.y, sh.y), 0.0f);
  o.z = fmaxf(fmaf(h.z, sc.z, sh.z), 0.0f);
  o.w = fmaxf(fmaf(h.w, sc.w, sh.w), 0.0f);
  ((float4*)io)[i] = o;
}

extern "C" void kernel_launch(void* const* d_in, const int* in_sizes, int n_in,
                              void* d_out, int out_size, void* d_ws,
                              size_t ws_size, hipStream_t stream) {
  const float* xyz1      = (const float*)d_in[0];
  const float* xyz2      = (const float*)d_in[1];
  const float* features1 = (const float*)d_in[2];
  const float* features2 = (const float*)d_in[3];
  const float* W1  = (const float*)d_in[4];
  const float* b1  = (const float*)d_in[5];
  const float* g1  = (const float*)d_in[6];
  const float* be1 = (const float*)d_in[7];
  const float* W2  = (const float*)d_in[8];
  const float* b2  = (const float*)d_in[9];
  const float* g2  = (const float*)d_in[10];
  const float* be2 = (const float*)d_in[11];
  float* out = (float*)d_out;

  // Workspace (~66 MB): h1 | w3 | idx3 | fp64 sums | scale/shift.
  // KNN partials (pd 6.3MB + pi 6.3MB) OVERLAY the h1 region: consumed by
  // knn_merge before gemm1 writes h1.
  char* wsb   = (char*)d_ws;
  float* h1   = (float*)wsb;                               // 64 MB
  float* w3   = (float*)(wsb + (size_t)MROWS * H1 * 4);
  int* idx3   = (int*)(wsb + (size_t)MROWS * H1 * 4 + (size_t)MROWS * 3 * 4);
  double* sums = (double*)((char*)idx3 + (size_t)MROWS * 3 * 4);
  double* sum1 = sums;
  double* sq1s = sums + 256;
  double* sum2 = sums + 512;
  double* sq2s = sums + 640;
  float* ss    = (float*)(sums + 768);
  float* scale1 = ss;
  float* shift1 = ss + 256;
  float* scale2 = ss + 512;
  float* shift2 = ss + 640;

  float* pd = h1;                                  // 6.3 MB overlay
  int*   pi = (int*)(h1 + (size_t)MROWS * NCHUNK * 3);  // next 6.3 MB

  hipMemsetAsync(sums, 0, 768 * sizeof(double), stream);

  knn_part_kernel<<<dim3(NPTS / 256, NCHUNK, BATCH), 256, 0, stream>>>(
      xyz1, xyz2, pd, pi);
  knn_merge_kernel<<<MROWS / 256, 256, 0, stream>>>(pd, pi, idx3, w3);
  gemm1_kernel<<<dim3(MROWS / BM, H1 / BN), 256, 0, stream>>>(
      features2, features1, idx3, w3, W1, b1, h1);
  colstats_kernel<<<256, H1, 0, stream>>>(h1, sum1, sq1s, H1, MROWS / 256);
  finalize_kernel<<<1, H1, 0, stream>>>(sum1, sq1s, g1, be1, scale1, shift1);
  gemm2_kernel<<<dim3(MROWS / BM, H2 / BN), 256, 0, stream>>>(h1, scale1, shift1,
                                                              W2, b2, out);
  colstats_kernel<<<256, H2, 0, stream>>>(out, sum2, sq2s, H2, MROWS / 256);
  finalize_kernel<<<1, H2, 0, stream>>>(sum2, sq2s, g2, be2, scale2, shift2);
  final_kernel<<<(MROWS * H2 / 4) / 256, 256, 0, stream>>>(out, scale2, shift2);
}